// Round 2
// baseline (841.942 us; speedup 1.0000x reference)
//
#include <hip/hip_runtime.h>

#define M_DIM 16384
#define N_DIM 4096
#define K_DIM 4096
#define NCLUST 16

#define BM 256
#define BN 256
#define BK 32
#define NT (K_DIM / BK)   // 128 K-tiles

typedef unsigned short u16;
typedef float floatx4 __attribute__((ext_vector_type(4)));
typedef short short8 __attribute__((ext_vector_type(8)));

typedef const unsigned int __attribute__((address_space(1))) gu32;
typedef unsigned int __attribute__((address_space(3))) lu32;

__device__ __forceinline__ u16 f2bf(float f) {
  union { float f; unsigned u; } a; a.f = f;
  unsigned u = a.u;
  unsigned r = (u + 0x7FFFu + ((u >> 16) & 1u)) >> 16;
  return (u16)r;
}

// ---------------- zero scratch accumulators ----------------
__global__ __launch_bounds__(256) void zero_kernel(float* __restrict__ p, int n) {
  int i = blockIdx.x * 256 + threadIdx.x;
  if (i < n) p[i] = 0.f;
}

// ---------------- z row-normalize -> bf16, plus copy z -> out1 ----------------
__global__ __launch_bounds__(256) void znorm_copy_kernel(const float* __restrict__ z,
                                                         float* __restrict__ out1,
                                                         u16* __restrict__ zn) {
  const int row = blockIdx.x;
  const int t = threadIdx.x;
  const size_t base = (size_t)row * K_DIM;
  const float4* zr = (const float4*)(z + base);
  float4 v[4];
  float ss = 0.f;
#pragma unroll
  for (int i = 0; i < 4; i++) {
    v[i] = zr[t + i * 256];
    ss += v[i].x * v[i].x + v[i].y * v[i].y + v[i].z * v[i].z + v[i].w * v[i].w;
  }
#pragma unroll
  for (int m = 1; m <= 32; m <<= 1) ss += __shfl_xor(ss, m, 64);
  __shared__ float red[4];
  if ((t & 63) == 0) red[t >> 6] = ss;
  __syncthreads();
  float tot = red[0] + red[1] + red[2] + red[3];
  float rn = 1.0f / fmaxf(sqrtf(tot), 1e-8f);
  float4* o1 = (float4*)(out1 + base);
  uint2* znr = (uint2*)(zn + base);
#pragma unroll
  for (int i = 0; i < 4; i++) {
    o1[t + i * 256] = v[i];
    uint2 p;
    p.x = (unsigned)f2bf(v[i].x * rn) | ((unsigned)f2bf(v[i].y * rn) << 16);
    p.y = (unsigned)f2bf(v[i].z * rn) | ((unsigned)f2bf(v[i].w * rn) << 16);
    znr[t + i * 256] = p;
  }
}

// ---------------- D column squared-norms ----------------
__global__ __launch_bounds__(256) void colsq_kernel(const float* __restrict__ D,
                                                    float* __restrict__ colsq) {
  const int col = blockIdx.x * 256 + threadIdx.x;
  const int r0 = blockIdx.y * 128;
  float ss = 0.f;
#pragma unroll 4
  for (int r = 0; r < 128; r++) {
    float d = D[(size_t)(r0 + r) * N_DIM + col];
    ss += d * d;
  }
  atomicAdd(&colsq[col], ss);
}

// ---------------- D col-normalize + transpose -> bf16 DnT[N][K] ----------------
__global__ __launch_bounds__(256) void dnt_kernel(const float* __restrict__ D,
                                                  const float* __restrict__ colsq,
                                                  u16* __restrict__ dnt) {
  __shared__ float tile[64][65];
  const int c0 = blockIdx.x * 64, r0 = blockIdx.y * 64;
  const int t = threadIdx.x;
  const int tr = t >> 4;          // 0..15
  const int tc = (t & 15) * 4;    // 0,4,..,60
#pragma unroll
  for (int i = 0; i < 4; i++) {
    int row = i * 16 + tr;
    float4 v = *(const float4*)(D + (size_t)(r0 + row) * N_DIM + c0 + tc);
    tile[row][tc + 0] = v.x; tile[row][tc + 1] = v.y;
    tile[row][tc + 2] = v.z; tile[row][tc + 3] = v.w;
  }
  __syncthreads();
#pragma unroll
  for (int i = 0; i < 4; i++) {
    int nl = i * 16 + tr;
    float rn = 1.0f / fmaxf(sqrtf(colsq[c0 + nl]), 1e-8f);
    unsigned lo = (unsigned)f2bf(tile[tc + 0][nl] * rn) | ((unsigned)f2bf(tile[tc + 1][nl] * rn) << 16);
    unsigned hi = (unsigned)f2bf(tile[tc + 2][nl] * rn) | ((unsigned)f2bf(tile[tc + 3][nl] * rn) << 16);
    uint2 p; p.x = lo; p.y = hi;
    *(uint2*)(dnt + (size_t)(c0 + nl) * K_DIM + r0 + tc) = p;
  }
}

// ---------------- GEMM: 256x256 tile, 8 waves (2Mx4N), BK=32 ----------------
// 4-deep LDS K-tile buffering, raw s_barrier + counted vmcnt (prefetch depth 3),
// setprio around MFMA clusters, LDS slot swizzle slot^((row>>1)&3) on both
// sides (pre-swizzled global source + swizzled ds_read). Epilogue: per-row
// square-sum over wave's 64 cols, LDS cross-wave reduce, plain store.
__global__ __launch_bounds__(512, 2) void gemm_kernel(const u16* __restrict__ zn,
                                                      const u16* __restrict__ dnt,
                                                      float* __restrict__ s_accum) {
  __shared__ u16 ldsA[4][BM * BK];   // 4 x 16 KB
  __shared__ u16 ldsB[4][BN * BK];   // 4 x 16 KB  -> 128 KB total

  const int t = threadIdx.x;
  const int w = t >> 6, l = t & 63;
  const int lr = l & 15;   // fragment row (A) / col (B)
  const int lk = l >> 4;   // k-slot (8 elems each)

  // XCD-aware swizzle: 1024 blocks, 8 XCDs, 128 contiguous work-ids per XCD
  const int bid = blockIdx.x;
  const int swz = (bid & 7) * 128 + (bid >> 3);
  const int bx = swz & 15;          // N-block (== cluster)
  const int by = swz >> 4;          // M-block
  const int bm = by * BM;
  const int bn = bx * BN;

  const int wm = (w >> 2) * 128;    // wave row offset (2 wave-rows)
  const int wn = (w & 3) * 64;      // wave col offset (4 wave-cols)

  // ---- staging source pointers (pre-swizzled) ----
  // chunk c for this thread: c1 = t (rows 0..127), c2 = t+512 (rows 128..255)
  const int srow = t >> 2;                    // 0..127
  const int sslot = t & 3;
  const int ssrc = sslot ^ ((srow >> 1) & 3); // same for srow+128
  const u16* pa0 = zn + (size_t)(bm + srow) * K_DIM + ssrc * 8;
  const u16* pa1 = zn + (size_t)(bm + srow + 128) * K_DIM + ssrc * 8;
  const u16* pb0 = dnt + (size_t)(bn + srow) * K_DIM + ssrc * 8;
  const u16* pb1 = dnt + (size_t)(bn + srow + 128) * K_DIM + ssrc * 8;

#define STAGE(TILE) do { \
    const int _kb = (TILE) * BK; \
    const int _bf = (TILE) & 3; \
    __builtin_amdgcn_global_load_lds((gu32*)(pa0 + _kb), (lu32*)&ldsA[_bf][(w * 64) * 8], 16, 0, 0); \
    __builtin_amdgcn_global_load_lds((gu32*)(pa1 + _kb), (lu32*)&ldsA[_bf][(512 + w * 64) * 8], 16, 0, 0); \
    __builtin_amdgcn_global_load_lds((gu32*)(pb0 + _kb), (lu32*)&ldsB[_bf][(w * 64) * 8], 16, 0, 0); \
    __builtin_amdgcn_global_load_lds((gu32*)(pb1 + _kb), (lu32*)&ldsB[_bf][(512 + w * 64) * 8], 16, 0, 0); \
  } while (0)

  // ---- fragment LDS element offsets (static-unrolled -> registers) ----
  int aOff[8], bOff[4];
#pragma unroll
  for (int m = 0; m < 8; m++) {
    int R = wm + m * 16 + lr;
    aOff[m] = R * BK + (lk ^ ((R >> 1) & 3)) * 8;
  }
#pragma unroll
  for (int n = 0; n < 4; n++) {
    int R = wn + n * 16 + lr;
    bOff[n] = R * BK + (lk ^ ((R >> 1) & 3)) * 8;
  }

  floatx4 acc[8][4] = {};

  // prologue: stage tiles 0,1,2 (12 loads in flight)
  STAGE(0); STAGE(1); STAGE(2);

#define KTILE(T, VNSTR, PREF) do { \
    asm volatile("s_waitcnt " VNSTR ::: "memory"); \
    __builtin_amdgcn_s_barrier(); \
    if (PREF) { STAGE((T) + 3); } \
    const u16* Ap = ldsA[(T) & 3]; \
    const u16* Bp = ldsB[(T) & 3]; \
    short8 bf[4], af[4]; \
    _Pragma("unroll") \
    for (int n = 0; n < 4; n++) bf[n] = *(const short8*)(Bp + bOff[n]); \
    _Pragma("unroll") \
    for (int mi = 0; mi < 4; mi++) af[mi] = *(const short8*)(Ap + aOff[mi]); \
    __builtin_amdgcn_s_setprio(1); \
    _Pragma("unroll") \
    for (int mi = 0; mi < 4; mi++) \
      _Pragma("unroll") \
      for (int n = 0; n < 4; n++) \
        acc[mi][n] = __builtin_amdgcn_mfma_f32_16x16x32_bf16(af[mi], bf[n], acc[mi][n], 0, 0, 0); \
    __builtin_amdgcn_s_setprio(0); \
    _Pragma("unroll") \
    for (int mi = 0; mi < 4; mi++) af[mi] = *(const short8*)(Ap + aOff[4 + mi]); \
    __builtin_amdgcn_s_setprio(1); \
    _Pragma("unroll") \
    for (int mi = 0; mi < 4; mi++) \
      _Pragma("unroll") \
      for (int n = 0; n < 4; n++) \
        acc[4 + mi][n] = __builtin_amdgcn_mfma_f32_16x16x32_bf16(af[mi], bf[n], acc[4 + mi][n], 0, 0, 0); \
    __builtin_amdgcn_s_setprio(0); \
  } while (0)

  for (int tt = 0; tt < NT - 3; ++tt) {
    KTILE(tt, "vmcnt(8)", true);       // in flight: t..t+2 (12) -> drain tile t
  }
  KTILE(NT - 3, "vmcnt(8)", false);    // in flight 12 -> drain NT-3
  KTILE(NT - 2, "vmcnt(4)", false);    // in flight 8  -> drain NT-2
  KTILE(NT - 1, "vmcnt(0)", false);    // in flight 4  -> drain NT-1

#undef KTILE
#undef STAGE

  // ---- epilogue: per-row sum of squares over this wave's 64 columns ----
  __syncthreads();                     // safe LDS reuse (drains everything)
  float* red = (float*)&ldsA[0][0];    // [256 rows][4 wave-cols] = 4 KB
#pragma unroll
  for (int m = 0; m < 8; m++) {
#pragma unroll
    for (int r = 0; r < 4; r++) {
      float v = 0.f;
#pragma unroll
      for (int n = 0; n < 4; n++) { float x = acc[m][n][r]; v += x * x; }
      v += __shfl_xor(v, 1, 64);
      v += __shfl_xor(v, 2, 64);
      v += __shfl_xor(v, 4, 64);
      v += __shfl_xor(v, 8, 64);
      if (lr == 0) {
        int lrow = wm + m * 16 + lk * 4 + r;   // 0..255 within block
        red[lrow * 4 + (w & 3)] = v;
      }
    }
  }
  __syncthreads();
  if (t < 256) {
    float s = red[t * 4 + 0] + red[t * 4 + 1] + red[t * 4 + 2] + red[t * 4 + 3];
    s_accum[(size_t)(bm + t) * NCLUST + bx] = s;
  }
}

// ---------------- softmax over 16 clusters per row ----------------
__global__ __launch_bounds__(256) void softmax_kernel(const float* __restrict__ s_accum,
                                                      float* __restrict__ out0) {
  int r = blockIdx.x * 256 + threadIdx.x;
  const float4* sp = (const float4*)(s_accum + (size_t)r * 16);
  float v[16];
#pragma unroll
  for (int i = 0; i < 4; i++) {
    float4 a = sp[i];
    v[i * 4 + 0] = a.x; v[i * 4 + 1] = a.y; v[i * 4 + 2] = a.z; v[i * 4 + 3] = a.w;
  }
  float mx = -1e30f;
#pragma unroll
  for (int i = 0; i < 16; i++) { v[i] *= 10.0f; mx = fmaxf(mx, v[i]); }   // 1/TEMP = 10; eta*d cancels
  float sum = 0.f;
#pragma unroll
  for (int i = 0; i < 16; i++) { v[i] = __expf(v[i] - mx); sum += v[i]; }
  float rs = 1.0f / sum;
  float4* op = (float4*)(out0 + (size_t)r * 16);
#pragma unroll
  for (int i = 0; i < 4; i++) {
    float4 a;
    a.x = v[i * 4 + 0] * rs; a.y = v[i * 4 + 1] * rs;
    a.z = v[i * 4 + 2] * rs; a.w = v[i * 4 + 3] * rs;
    op[i] = a;
  }
}

extern "C" void kernel_launch(void* const* d_in, const int* in_sizes, int n_in,
                              void* d_out, int out_size, void* d_ws, size_t ws_size,
                              hipStream_t stream) {
  const float* z = (const float*)d_in[0];
  const float* D = (const float*)d_in[1];
  float* out0 = (float*)d_out;
  float* out1 = out0 + (size_t)M_DIM * NCLUST;

  char* ws = (char*)d_ws;
  u16* zn   = (u16*)ws;                                               // 128 MB
  u16* dnt  = (u16*)(ws + (size_t)M_DIM * K_DIM * 2);                 // 32 MB
  float* colsq   = (float*)(ws + (size_t)M_DIM * K_DIM * 2 + (size_t)N_DIM * K_DIM * 2);
  float* s_accum = colsq + N_DIM;

  zero_kernel<<<(N_DIM + 255) / 256, 256, 0, stream>>>(colsq, N_DIM);
  znorm_copy_kernel<<<M_DIM, 256, 0, stream>>>(z, out1, zn);
  colsq_kernel<<<dim3(N_DIM / 256, N_DIM / 128), 256, 0, stream>>>(D, colsq);
  dnt_kernel<<<dim3(N_DIM / 64, N_DIM / 64), 256, 0, stream>>>(D, colsq, dnt);
  gemm_kernel<<<(M_DIM / BM) * (N_DIM / BN), 512, 0, stream>>>(zn, dnt, s_accum);
  softmax_kernel<<<M_DIM / 256, 256, 0, stream>>>(s_accum, out0);
}

// Round 3
// 645.212 us; speedup vs baseline: 1.3049x; 1.3049x over previous
//
#include <hip/hip_runtime.h>

#define M_DIM 16384
#define N_DIM 4096
#define K_DIM 4096
#define NCLUST 16

#define BM 256
#define BN 256
#define BK 64
#define NT (K_DIM / BK)   // 64 K-tiles

typedef unsigned short u16;
typedef float floatx4 __attribute__((ext_vector_type(4)));
typedef short short8 __attribute__((ext_vector_type(8)));

typedef const unsigned int __attribute__((address_space(1))) gu32;
typedef unsigned int __attribute__((address_space(3))) lu32;

__device__ __forceinline__ u16 f2bf(float f) {
  union { float f; unsigned u; } a; a.f = f;
  unsigned u = a.u;
  unsigned r = (u + 0x7FFFu + ((u >> 16) & 1u)) >> 16;
  return (u16)r;
}

// ---------------- zero scratch accumulators ----------------
__global__ __launch_bounds__(256) void zero_kernel(float* __restrict__ p, int n) {
  int i = blockIdx.x * 256 + threadIdx.x;
  if (i < n) p[i] = 0.f;
}

// ---------------- z row-normalize -> bf16, plus copy z -> out1 ----------------
__global__ __launch_bounds__(256) void znorm_copy_kernel(const float* __restrict__ z,
                                                         float* __restrict__ out1,
                                                         u16* __restrict__ zn) {
  const int row = blockIdx.x;
  const int t = threadIdx.x;
  const size_t base = (size_t)row * K_DIM;
  const float4* zr = (const float4*)(z + base);
  float4 v[4];
  float ss = 0.f;
#pragma unroll
  for (int i = 0; i < 4; i++) {
    v[i] = zr[t + i * 256];
    ss += v[i].x * v[i].x + v[i].y * v[i].y + v[i].z * v[i].z + v[i].w * v[i].w;
  }
#pragma unroll
  for (int m = 1; m <= 32; m <<= 1) ss += __shfl_xor(ss, m, 64);
  __shared__ float red[4];
  if ((t & 63) == 0) red[t >> 6] = ss;
  __syncthreads();
  float tot = red[0] + red[1] + red[2] + red[3];
  float rn = 1.0f / fmaxf(sqrtf(tot), 1e-8f);
  float4* o1 = (float4*)(out1 + base);
  uint2* znr = (uint2*)(zn + base);
#pragma unroll
  for (int i = 0; i < 4; i++) {
    o1[t + i * 256] = v[i];
    uint2 p;
    p.x = (unsigned)f2bf(v[i].x * rn) | ((unsigned)f2bf(v[i].y * rn) << 16);
    p.y = (unsigned)f2bf(v[i].z * rn) | ((unsigned)f2bf(v[i].w * rn) << 16);
    znr[t + i * 256] = p;
  }
}

// ---------------- D column squared-norms ----------------
__global__ __launch_bounds__(256) void colsq_kernel(const float* __restrict__ D,
                                                    float* __restrict__ colsq) {
  const int col = blockIdx.x * 256 + threadIdx.x;
  const int r0 = blockIdx.y * 128;
  float ss = 0.f;
#pragma unroll 4
  for (int r = 0; r < 128; r++) {
    float d = D[(size_t)(r0 + r) * N_DIM + col];
    ss += d * d;
  }
  atomicAdd(&colsq[col], ss);
}

// ---------------- D col-normalize + transpose -> bf16 DnT[N][K] ----------------
__global__ __launch_bounds__(256) void dnt_kernel(const float* __restrict__ D,
                                                  const float* __restrict__ colsq,
                                                  u16* __restrict__ dnt) {
  __shared__ float tile[64][65];
  const int c0 = blockIdx.x * 64, r0 = blockIdx.y * 64;
  const int t = threadIdx.x;
  const int tr = t >> 4;          // 0..15
  const int tc = (t & 15) * 4;    // 0,4,..,60
#pragma unroll
  for (int i = 0; i < 4; i++) {
    int row = i * 16 + tr;
    float4 v = *(const float4*)(D + (size_t)(r0 + row) * N_DIM + c0 + tc);
    tile[row][tc + 0] = v.x; tile[row][tc + 1] = v.y;
    tile[row][tc + 2] = v.z; tile[row][tc + 3] = v.w;
  }
  __syncthreads();
#pragma unroll
  for (int i = 0; i < 4; i++) {
    int nl = i * 16 + tr;
    float rn = 1.0f / fmaxf(sqrtf(colsq[c0 + nl]), 1e-8f);
    unsigned lo = (unsigned)f2bf(tile[tc + 0][nl] * rn) | ((unsigned)f2bf(tile[tc + 1][nl] * rn) << 16);
    unsigned hi = (unsigned)f2bf(tile[tc + 2][nl] * rn) | ((unsigned)f2bf(tile[tc + 3][nl] * rn) << 16);
    uint2 p; p.x = lo; p.y = hi;
    *(uint2*)(dnt + (size_t)(c0 + nl) * K_DIM + r0 + tc) = p;
  }
}

// ---------------- GEMM: 256x256, BK=64, 8 waves, m201-style 4-phase/K-tile ----------------
// Per phase: {ds_read register subtile; stage ONE half-tile (2 x global_load_lds);
// [counted vmcnt at ph4]; s_barrier; lgkmcnt(0); setprio(1); 16 MFMA; setprio(0); s_barrier}.
// Halves: Ah(mh) = rows {mh*64.., mh*64+128..}; Bh(nh) = rows {nh*32 + g*64 ..} so each
// phase's ds_reads and staged region are disjoint. Stage schedule per iter t:
// ph1: Ah1(t+1)->nb, ph2: Bh0(t+1)->nb, ph3: Ah0(t+2)->cb, ph4: Bh1(t+2)->cb + vmcnt(4).
__global__ __launch_bounds__(512, 2) void gemm_kernel(const u16* __restrict__ zn,
                                                      const u16* __restrict__ dnt,
                                                      float* __restrict__ s_accum) {
  __shared__ u16 ldsA[2][BM * BK];   // 2 x 32 KB
  __shared__ u16 ldsB[2][BN * BK];   // 2 x 32 KB -> 128 KB

  const int t = threadIdx.x;
  const int w = t >> 6, l = t & 63;
  const int lr = l & 15, lk = l >> 4;

  // XCD-aware swizzle: 1024 blocks, 8 XCDs, 128 contiguous work-ids per XCD
  const int bid = blockIdx.x;
  const int swz = (bid & 7) * 128 + (bid >> 3);
  const int bx = swz & 15, by = swz >> 4;
  const int bm = by * BM, bn = bx * BN;
  const int wm = (w >> 2) * 128, wn = (w & 3) * 64;

  // ---- staging pointers (pre-swizzled global source), LDS wave-uniform dests ----
  const int tr8 = t >> 3, ts = t & 7;
  const u16* pA[2][2]; const u16* pB[2][2];
  int aDst[2][2], bDst[2][2];
#pragma unroll
  for (int mh = 0; mh < 2; mh++)
#pragma unroll
    for (int r = 0; r < 2; r++) {
      int row = mh * 64 + r * 128 + tr8;
      int f = (row >> 1) & 3;
      pA[mh][r] = zn + (size_t)(bm + row) * K_DIM + (size_t)((ts ^ f) * 8);
      aDst[mh][r] = (mh * 64 + r * 128) * BK + w * 512;
    }
#pragma unroll
  for (int nh = 0; nh < 2; nh++)
#pragma unroll
    for (int r = 0; r < 2; r++) {
      int row = nh * 32 + (2 * r + (t >> 8)) * 64 + (tr8 & 31);
      int f = (row >> 1) & 3;
      pB[nh][r] = dnt + (size_t)(bn + row) * K_DIM + (size_t)((ts ^ f) * 8);
      bDst[nh][r] = (nh * 32 + (2 * r + (w >> 2)) * 64 + (w & 3) * 8) * BK;
    }

#define STAGE_AH(BUF, MH, KT) do { \
    __builtin_amdgcn_global_load_lds((gu32*)(pA[MH][0] + (KT) * BK), (lu32*)&ldsA[BUF][aDst[MH][0]], 16, 0, 0); \
    __builtin_amdgcn_global_load_lds((gu32*)(pA[MH][1] + (KT) * BK), (lu32*)&ldsA[BUF][aDst[MH][1]], 16, 0, 0); \
  } while (0)
#define STAGE_BH(BUF, NH, KT) do { \
    __builtin_amdgcn_global_load_lds((gu32*)(pB[NH][0] + (KT) * BK), (lu32*)&ldsB[BUF][bDst[NH][0]], 16, 0, 0); \
    __builtin_amdgcn_global_load_lds((gu32*)(pB[NH][1] + (KT) * BK), (lu32*)&ldsB[BUF][bDst[NH][1]], 16, 0, 0); \
  } while (0)

  // ---- ds_read fragment offsets (swizzled) ----
  int aOff[8], bOff[4];
#pragma unroll
  for (int m = 0; m < 8; m++) {
    int row = wm + (m >> 2) * 64 + (m & 3) * 16 + lr;
    aOff[m] = row * BK + (lk ^ ((row >> 1) & 3)) * 8;
  }
#pragma unroll
  for (int n = 0; n < 4; n++) {
    int row = wn + (n >> 1) * 32 + (n & 1) * 16 + lr;
    bOff[n] = row * BK + (lk ^ ((row >> 1) & 3)) * 8;
  }

  short8 af[4][2], bf[2][2];
  floatx4 acc[8][4] = {};

#define PHASE(AB, BB, MH, NH, RDA, RDB, STAGE_STMT, WAIT_STMT) do { \
    if (RDA) { \
      _Pragma("unroll") \
      for (int mi = 0; mi < 4; mi++) { \
        af[mi][0] = *(const short8*)((AB) + aOff[(MH) * 4 + mi]); \
        af[mi][1] = *(const short8*)((AB) + aOff[(MH) * 4 + mi] + 32); \
      } } \
    if (RDB) { \
      _Pragma("unroll") \
      for (int ni = 0; ni < 2; ni++) { \
        bf[ni][0] = *(const short8*)((BB) + bOff[(NH) * 2 + ni]); \
        bf[ni][1] = *(const short8*)((BB) + bOff[(NH) * 2 + ni] + 32); \
      } } \
    STAGE_STMT; \
    WAIT_STMT; \
    __builtin_amdgcn_s_barrier(); \
    asm volatile("s_waitcnt lgkmcnt(0)" ::: "memory"); \
    __builtin_amdgcn_s_setprio(1); \
    _Pragma("unroll") \
    for (int kk = 0; kk < 2; kk++) \
      _Pragma("unroll") \
      for (int mi = 0; mi < 4; mi++) \
        _Pragma("unroll") \
        for (int ni = 0; ni < 2; ni++) \
          acc[(MH) * 4 + mi][(NH) * 2 + ni] = __builtin_amdgcn_mfma_f32_16x16x32_bf16( \
              af[mi][kk], bf[ni][kk], acc[(MH) * 4 + mi][(NH) * 2 + ni], 0, 0, 0); \
    __builtin_amdgcn_s_setprio(0); \
    __builtin_amdgcn_s_barrier(); \
  } while (0)

  // prologue: tile0 fully + Ah0(1), Bh1(1); drain tile0, keep 2 halves in flight
  STAGE_AH(0, 0, 0); STAGE_AH(0, 1, 0); STAGE_BH(0, 0, 0); STAGE_BH(0, 1, 0);
  STAGE_AH(1, 0, 1); STAGE_BH(1, 1, 1);
  asm volatile("s_waitcnt vmcnt(4)" ::: "memory");
  __builtin_amdgcn_s_barrier();

  for (int kt = 0; kt < NT - 2; ++kt) {
    const int cb = kt & 1, nb = cb ^ 1;
    const u16* Ac = ldsA[cb]; const u16* Bc = ldsB[cb];
    PHASE(Ac, Bc, 0, 0, 1, 1, STAGE_AH(nb, 1, kt + 1), ((void)0));
    PHASE(Ac, Bc, 0, 1, 0, 1, STAGE_BH(nb, 0, kt + 1), ((void)0));
    PHASE(Ac, Bc, 1, 1, 1, 0, STAGE_AH(cb, 0, kt + 2), ((void)0));
    PHASE(Ac, Bc, 1, 0, 0, 1, STAGE_BH(cb, 1, kt + 2),
          asm volatile("s_waitcnt vmcnt(4)" ::: "memory"));
  }
  { // kt = NT-2: stage only tile NT-1's remaining halves; full drain at ph4
    const int cb = (NT - 2) & 1, nb = cb ^ 1;
    const u16* Ac = ldsA[cb]; const u16* Bc = ldsB[cb];
    PHASE(Ac, Bc, 0, 0, 1, 1, STAGE_AH(nb, 1, NT - 1), ((void)0));
    PHASE(Ac, Bc, 0, 1, 0, 1, STAGE_BH(nb, 0, NT - 1), ((void)0));
    PHASE(Ac, Bc, 1, 1, 1, 0, ((void)0), ((void)0));
    PHASE(Ac, Bc, 1, 0, 0, 1, ((void)0),
          asm volatile("s_waitcnt vmcnt(0)" ::: "memory"));
  }
  { // kt = NT-1: compute only
    const int cb = (NT - 1) & 1;
    const u16* Ac = ldsA[cb]; const u16* Bc = ldsB[cb];
    PHASE(Ac, Bc, 0, 0, 1, 1, ((void)0), ((void)0));
    PHASE(Ac, Bc, 0, 1, 0, 1, ((void)0), ((void)0));
    PHASE(Ac, Bc, 1, 1, 1, 0, ((void)0), ((void)0));
    PHASE(Ac, Bc, 1, 0, 0, 1, ((void)0), ((void)0));
  }

#undef PHASE
#undef STAGE_AH
#undef STAGE_BH

  // ---- epilogue: per-row sum of squares over this wave's 64 columns ----
  __syncthreads();
  float* red = (float*)&ldsA[0][0];    // [256 rows][4 wave-cols]
#pragma unroll
  for (int m = 0; m < 8; m++) {
#pragma unroll
    for (int r = 0; r < 4; r++) {
      float v = 0.f;
#pragma unroll
      for (int n = 0; n < 4; n++) { float x = acc[m][n][r]; v += x * x; }
      v += __shfl_xor(v, 1, 64);
      v += __shfl_xor(v, 2, 64);
      v += __shfl_xor(v, 4, 64);
      v += __shfl_xor(v, 8, 64);
      if (lr == 0) {
        int lrow = wm + (m >> 2) * 64 + (m & 3) * 16 + lk * 4 + r;
        red[lrow * 4 + (w & 3)] = v;
      }
    }
  }
  __syncthreads();
  if (t < 256) {
    float s = red[t * 4 + 0] + red[t * 4 + 1] + red[t * 4 + 2] + red[t * 4 + 3];
    s_accum[(size_t)(bm + t) * NCLUST + bx] = s;
  }
}

// ---------------- softmax over 16 clusters per row ----------------
__global__ __launch_bounds__(256) void softmax_kernel(const float* __restrict__ s_accum,
                                                      float* __restrict__ out0) {
  int r = blockIdx.x * 256 + threadIdx.x;
  const float4* sp = (const float4*)(s_accum + (size_t)r * 16);
  float v[16];
#pragma unroll
  for (int i = 0; i < 4; i++) {
    float4 a = sp[i];
    v[i * 4 + 0] = a.x; v[i * 4 + 1] = a.y; v[i * 4 + 2] = a.z; v[i * 4 + 3] = a.w;
  }
  float mx = -1e30f;
#pragma unroll
  for (int i = 0; i < 16; i++) { v[i] *= 10.0f; mx = fmaxf(mx, v[i]); }   // 1/TEMP = 10; eta*d cancels
  float sum = 0.f;
#pragma unroll
  for (int i = 0; i < 16; i++) { v[i] = __expf(v[i] - mx); sum += v[i]; }
  float rs = 1.0f / sum;
  float4* op = (float4*)(out0 + (size_t)r * 16);
#pragma unroll
  for (int i = 0; i < 4; i++) {
    float4 a;
    a.x = v[i * 4 + 0] * rs; a.y = v[i * 4 + 1] * rs;
    a.z = v[i * 4 + 2] * rs; a.w = v[i * 4 + 3] * rs;
    op[i] = a;
  }
}

extern "C" void kernel_launch(void* const* d_in, const int* in_sizes, int n_in,
                              void* d_out, int out_size, void* d_ws, size_t ws_size,
                              hipStream_t stream) {
  const float* z = (const float*)d_in[0];
  const float* D = (const float*)d_in[1];
  float* out0 = (float*)d_out;
  float* out1 = out0 + (size_t)M_DIM * NCLUST;

  char* ws = (char*)d_ws;
  u16* zn   = (u16*)ws;                                               // 128 MB
  u16* dnt  = (u16*)(ws + (size_t)M_DIM * K_DIM * 2);                 // 32 MB
  float* colsq   = (float*)(ws + (size_t)M_DIM * K_DIM * 2 + (size_t)N_DIM * K_DIM * 2);
  float* s_accum = colsq + N_DIM;

  zero_kernel<<<(N_DIM + 255) / 256, 256, 0, stream>>>(colsq, N_DIM);
  znorm_copy_kernel<<<M_DIM, 256, 0, stream>>>(z, out1, zn);
  colsq_kernel<<<dim3(N_DIM / 256, N_DIM / 128), 256, 0, stream>>>(D, colsq);
  dnt_kernel<<<dim3(N_DIM / 64, N_DIM / 64), 256, 0, stream>>>(D, colsq, dnt);
  gemm_kernel<<<(M_DIM / BM) * (N_DIM / BN), 512, 0, stream>>>(zn, dnt, s_accum);
  softmax_kernel<<<M_DIM / 256, 256, 0, stream>>>(s_accum, out0);
}

// Round 4
// 619.484 us; speedup vs baseline: 1.3591x; 1.0415x over previous
//
#include <hip/hip_runtime.h>

#define M_DIM 16384
#define N_DIM 4096
#define K_DIM 4096
#define NCLUST 16

#define BM 256
#define BN 256
#define BK 64
#define NT (K_DIM / BK)   // 64 K-tiles

typedef unsigned short u16;
typedef float floatx4 __attribute__((ext_vector_type(4)));
typedef short short8 __attribute__((ext_vector_type(8)));

typedef const unsigned int __attribute__((address_space(1))) gu32;
typedef unsigned int __attribute__((address_space(3))) lu32;

__device__ __forceinline__ u16 f2bf(float f) {
  union { float f; unsigned u; } a; a.f = f;
  unsigned u = a.u;
  unsigned r = (u + 0x7FFFu + ((u >> 16) & 1u)) >> 16;
  return (u16)r;
}

// ---------------- zero scratch accumulators ----------------
__global__ __launch_bounds__(256) void zero_kernel(float* __restrict__ p, int n) {
  int i = blockIdx.x * 256 + threadIdx.x;
  if (i < n) p[i] = 0.f;
}

// ---------------- z row-normalize -> bf16, plus copy z -> out1 ----------------
__global__ __launch_bounds__(256) void znorm_copy_kernel(const float* __restrict__ z,
                                                         float* __restrict__ out1,
                                                         u16* __restrict__ zn) {
  const int row = blockIdx.x;
  const int t = threadIdx.x;
  const size_t base = (size_t)row * K_DIM;
  const float4* zr = (const float4*)(z + base);
  float4 v[4];
  float ss = 0.f;
#pragma unroll
  for (int i = 0; i < 4; i++) {
    v[i] = zr[t + i * 256];
    ss += v[i].x * v[i].x + v[i].y * v[i].y + v[i].z * v[i].z + v[i].w * v[i].w;
  }
#pragma unroll
  for (int m = 1; m <= 32; m <<= 1) ss += __shfl_xor(ss, m, 64);
  __shared__ float red[4];
  if ((t & 63) == 0) red[t >> 6] = ss;
  __syncthreads();
  float tot = red[0] + red[1] + red[2] + red[3];
  float rn = 1.0f / fmaxf(sqrtf(tot), 1e-8f);
  float4* o1 = (float4*)(out1 + base);
  uint2* znr = (uint2*)(zn + base);
#pragma unroll
  for (int i = 0; i < 4; i++) {
    o1[t + i * 256] = v[i];
    uint2 p;
    p.x = (unsigned)f2bf(v[i].x * rn) | ((unsigned)f2bf(v[i].y * rn) << 16);
    p.y = (unsigned)f2bf(v[i].z * rn) | ((unsigned)f2bf(v[i].w * rn) << 16);
    znr[t + i * 256] = p;
  }
}

// ---------------- D column squared-norms ----------------
__global__ __launch_bounds__(256) void colsq_kernel(const float* __restrict__ D,
                                                    float* __restrict__ colsq) {
  const int col = blockIdx.x * 256 + threadIdx.x;
  const int r0 = blockIdx.y * 128;
  float ss = 0.f;
#pragma unroll 4
  for (int r = 0; r < 128; r++) {
    float d = D[(size_t)(r0 + r) * N_DIM + col];
    ss += d * d;
  }
  atomicAdd(&colsq[col], ss);
}

// ---------------- D col-normalize + transpose -> bf16 DnT[N][K] ----------------
__global__ __launch_bounds__(256) void dnt_kernel(const float* __restrict__ D,
                                                  const float* __restrict__ colsq,
                                                  u16* __restrict__ dnt) {
  __shared__ float tile[64][65];
  const int c0 = blockIdx.x * 64, r0 = blockIdx.y * 64;
  const int t = threadIdx.x;
  const int tr = t >> 4;          // 0..15
  const int tc = (t & 15) * 4;    // 0,4,..,60
#pragma unroll
  for (int i = 0; i < 4; i++) {
    int row = i * 16 + tr;
    float4 v = *(const float4*)(D + (size_t)(r0 + row) * N_DIM + c0 + tc);
    tile[row][tc + 0] = v.x; tile[row][tc + 1] = v.y;
    tile[row][tc + 2] = v.z; tile[row][tc + 3] = v.w;
  }
  __syncthreads();
#pragma unroll
  for (int i = 0; i < 4; i++) {
    int nl = i * 16 + tr;
    float rn = 1.0f / fmaxf(sqrtf(colsq[c0 + nl]), 1e-8f);
    unsigned lo = (unsigned)f2bf(tile[tc + 0][nl] * rn) | ((unsigned)f2bf(tile[tc + 1][nl] * rn) << 16);
    unsigned hi = (unsigned)f2bf(tile[tc + 2][nl] * rn) | ((unsigned)f2bf(tile[tc + 3][nl] * rn) << 16);
    uint2 p; p.x = lo; p.y = hi;
    *(uint2*)(dnt + (size_t)(c0 + nl) * K_DIM + r0 + tc) = p;
  }
}

// ---------------- GEMM: 256x256, BK=64, 8 waves, 4-phase/K-tile ----------------
// T2 fix vs R3: rows are 128 B (= 32 banks), so swizzle must spread across all
// 8 16B-slots of a row: slot' = slot ^ (row & 7). Applied on BOTH sides:
// pre-swizzled global source for global_load_lds (linear LDS dest) and the
// swizzled ds_read offsets (kk=1 half at offset ^ 32 elements, since
// (lk+4)^f == (lk^f)^4). Everything else identical to R3.
__global__ __launch_bounds__(512, 2) void gemm_kernel(const u16* __restrict__ zn,
                                                      const u16* __restrict__ dnt,
                                                      float* __restrict__ s_accum) {
  __shared__ u16 ldsA[2][BM * BK];   // 2 x 32 KB
  __shared__ u16 ldsB[2][BN * BK];   // 2 x 32 KB -> 128 KB

  const int t = threadIdx.x;
  const int w = t >> 6, l = t & 63;
  const int lr = l & 15, lk = l >> 4;

  // XCD-aware swizzle: 1024 blocks, 8 XCDs, 128 contiguous work-ids per XCD
  const int bid = blockIdx.x;
  const int swz = (bid & 7) * 128 + (bid >> 3);
  const int bx = swz & 15, by = swz >> 4;
  const int bm = by * BM, bn = bx * BN;
  const int wm = (w >> 2) * 128, wn = (w & 3) * 64;

  // ---- staging source pointers (pre-swizzled), LDS wave-uniform dests ----
  const int tr8 = t >> 3, ts = t & 7;
  const int ssrc = ts ^ (tr8 & 7);            // row & 7 == tr8 & 7 for all staged rows
  const u16* pA[2][2]; const u16* pB[2][2];
  int aDst[2][2], bDst[2][2];
#pragma unroll
  for (int mh = 0; mh < 2; mh++)
#pragma unroll
    for (int r = 0; r < 2; r++) {
      int row = mh * 64 + r * 128 + tr8;
      pA[mh][r] = zn + (size_t)(bm + row) * K_DIM + (size_t)(ssrc * 8);
      aDst[mh][r] = (mh * 64 + r * 128) * BK + w * 512;
    }
#pragma unroll
  for (int nh = 0; nh < 2; nh++)
#pragma unroll
    for (int r = 0; r < 2; r++) {
      int row = nh * 32 + (2 * r + (t >> 8)) * 64 + (tr8 & 31);
      pB[nh][r] = dnt + (size_t)(bn + row) * K_DIM + (size_t)(ssrc * 8);
      bDst[nh][r] = (nh * 32 + (2 * r + (w >> 2)) * 64 + (w & 3) * 8) * BK;
    }

#define STAGE_AH(BUF, MH, KT) do { \
    __builtin_amdgcn_global_load_lds((gu32*)(pA[MH][0] + (KT) * BK), (lu32*)&ldsA[BUF][aDst[MH][0]], 16, 0, 0); \
    __builtin_amdgcn_global_load_lds((gu32*)(pA[MH][1] + (KT) * BK), (lu32*)&ldsA[BUF][aDst[MH][1]], 16, 0, 0); \
  } while (0)
#define STAGE_BH(BUF, NH, KT) do { \
    __builtin_amdgcn_global_load_lds((gu32*)(pB[NH][0] + (KT) * BK), (lu32*)&ldsB[BUF][bDst[NH][0]], 16, 0, 0); \
    __builtin_amdgcn_global_load_lds((gu32*)(pB[NH][1] + (KT) * BK), (lu32*)&ldsB[BUF][bDst[NH][1]], 16, 0, 0); \
  } while (0)

  // ---- ds_read fragment offsets (full 3-bit row swizzle) ----
  int aOff[8], bOff[4];
#pragma unroll
  for (int m = 0; m < 8; m++) {
    int row = wm + (m >> 2) * 64 + (m & 3) * 16 + lr;
    aOff[m] = row * BK + ((lk ^ (row & 7)) * 8);
  }
#pragma unroll
  for (int n = 0; n < 4; n++) {
    int row = wn + (n >> 1) * 32 + (n & 1) * 16 + lr;
    bOff[n] = row * BK + ((lk ^ (row & 7)) * 8);
  }

  short8 af[4][2], bf[2][2];
  floatx4 acc[8][4] = {};

#define PHASE(AB, BB, MH, NH, RDA, RDB, STAGE_STMT, WAIT_STMT) do { \
    if (RDA) { \
      _Pragma("unroll") \
      for (int mi = 0; mi < 4; mi++) { \
        af[mi][0] = *(const short8*)((AB) + aOff[(MH) * 4 + mi]); \
        af[mi][1] = *(const short8*)((AB) + (aOff[(MH) * 4 + mi] ^ 32)); \
      } } \
    if (RDB) { \
      _Pragma("unroll") \
      for (int ni = 0; ni < 2; ni++) { \
        bf[ni][0] = *(const short8*)((BB) + bOff[(NH) * 2 + ni]); \
        bf[ni][1] = *(const short8*)((BB) + (bOff[(NH) * 2 + ni] ^ 32)); \
      } } \
    STAGE_STMT; \
    WAIT_STMT; \
    __builtin_amdgcn_s_barrier(); \
    asm volatile("s_waitcnt lgkmcnt(0)" ::: "memory"); \
    __builtin_amdgcn_s_setprio(1); \
    _Pragma("unroll") \
    for (int kk = 0; kk < 2; kk++) \
      _Pragma("unroll") \
      for (int mi = 0; mi < 4; mi++) \
        _Pragma("unroll") \
        for (int ni = 0; ni < 2; ni++) \
          acc[(MH) * 4 + mi][(NH) * 2 + ni] = __builtin_amdgcn_mfma_f32_16x16x32_bf16( \
              af[mi][kk], bf[ni][kk], acc[(MH) * 4 + mi][(NH) * 2 + ni], 0, 0, 0); \
    __builtin_amdgcn_s_setprio(0); \
    __builtin_amdgcn_s_barrier(); \
  } while (0)

  // prologue: tile0 fully + Ah0(1), Bh1(1); drain tile0, keep 2 halves in flight
  STAGE_AH(0, 0, 0); STAGE_AH(0, 1, 0); STAGE_BH(0, 0, 0); STAGE_BH(0, 1, 0);
  STAGE_AH(1, 0, 1); STAGE_BH(1, 1, 1);
  asm volatile("s_waitcnt vmcnt(4)" ::: "memory");
  __builtin_amdgcn_s_barrier();

  for (int kt = 0; kt < NT - 2; ++kt) {
    const int cb = kt & 1, nb = cb ^ 1;
    const u16* Ac = ldsA[cb]; const u16* Bc = ldsB[cb];
    PHASE(Ac, Bc, 0, 0, 1, 1, STAGE_AH(nb, 1, kt + 1), ((void)0));
    PHASE(Ac, Bc, 0, 1, 0, 1, STAGE_BH(nb, 0, kt + 1), ((void)0));
    PHASE(Ac, Bc, 1, 1, 1, 0, STAGE_AH(cb, 0, kt + 2), ((void)0));
    PHASE(Ac, Bc, 1, 0, 0, 1, STAGE_BH(cb, 1, kt + 2),
          asm volatile("s_waitcnt vmcnt(4)" ::: "memory"));
  }
  { // kt = NT-2: stage only tile NT-1's remaining halves; full drain at ph4
    const int cb = (NT - 2) & 1, nb = cb ^ 1;
    const u16* Ac = ldsA[cb]; const u16* Bc = ldsB[cb];
    PHASE(Ac, Bc, 0, 0, 1, 1, STAGE_AH(nb, 1, NT - 1), ((void)0));
    PHASE(Ac, Bc, 0, 1, 0, 1, STAGE_BH(nb, 0, NT - 1), ((void)0));
    PHASE(Ac, Bc, 1, 1, 1, 0, ((void)0), ((void)0));
    PHASE(Ac, Bc, 1, 0, 0, 1, ((void)0),
          asm volatile("s_waitcnt vmcnt(0)" ::: "memory"));
  }
  { // kt = NT-1: compute only
    const int cb = (NT - 1) & 1;
    const u16* Ac = ldsA[cb]; const u16* Bc = ldsB[cb];
    PHASE(Ac, Bc, 0, 0, 1, 1, ((void)0), ((void)0));
    PHASE(Ac, Bc, 0, 1, 0, 1, ((void)0), ((void)0));
    PHASE(Ac, Bc, 1, 1, 1, 0, ((void)0), ((void)0));
    PHASE(Ac, Bc, 1, 0, 0, 1, ((void)0), ((void)0));
  }

#undef PHASE
#undef STAGE_AH
#undef STAGE_BH

  // ---- epilogue: per-row sum of squares over this wave's 64 columns ----
  __syncthreads();
  float* red = (float*)&ldsA[0][0];    // [256 rows][4 wave-cols]
#pragma unroll
  for (int m = 0; m < 8; m++) {
#pragma unroll
    for (int r = 0; r < 4; r++) {
      float v = 0.f;
#pragma unroll
      for (int n = 0; n < 4; n++) { float x = acc[m][n][r]; v += x * x; }
      v += __shfl_xor(v, 1, 64);
      v += __shfl_xor(v, 2, 64);
      v += __shfl_xor(v, 4, 64);
      v += __shfl_xor(v, 8, 64);
      if (lr == 0) {
        int lrow = wm + (m >> 2) * 64 + (m & 3) * 16 + lk * 4 + r;
        red[lrow * 4 + (w & 3)] = v;
      }
    }
  }
  __syncthreads();
  if (t < 256) {
    float s = red[t * 4 + 0] + red[t * 4 + 1] + red[t * 4 + 2] + red[t * 4 + 3];
    s_accum[(size_t)(bm + t) * NCLUST + bx] = s;
  }
}

// ---------------- softmax over 16 clusters per row ----------------
__global__ __launch_bounds__(256) void softmax_kernel(const float* __restrict__ s_accum,
                                                      float* __restrict__ out0) {
  int r = blockIdx.x * 256 + threadIdx.x;
  const float4* sp = (const float4*)(s_accum + (size_t)r * 16);
  float v[16];
#pragma unroll
  for (int i = 0; i < 4; i++) {
    float4 a = sp[i];
    v[i * 4 + 0] = a.x; v[i * 4 + 1] = a.y; v[i * 4 + 2] = a.z; v[i * 4 + 3] = a.w;
  }
  float mx = -1e30f;
#pragma unroll
  for (int i = 0; i < 16; i++) { v[i] *= 10.0f; mx = fmaxf(mx, v[i]); }   // 1/TEMP = 10; eta*d cancels
  float sum = 0.f;
#pragma unroll
  for (int i = 0; i < 16; i++) { v[i] = __expf(v[i] - mx); sum += v[i]; }
  float rs = 1.0f / sum;
  float4* op = (float4*)(out0 + (size_t)r * 16);
#pragma unroll
  for (int i = 0; i < 4; i++) {
    float4 a;
    a.x = v[i * 4 + 0] * rs; a.y = v[i * 4 + 1] * rs;
    a.z = v[i * 4 + 2] * rs; a.w = v[i * 4 + 3] * rs;
    op[i] = a;
  }
}

extern "C" void kernel_launch(void* const* d_in, const int* in_sizes, int n_in,
                              void* d_out, int out_size, void* d_ws, size_t ws_size,
                              hipStream_t stream) {
  const float* z = (const float*)d_in[0];
  const float* D = (const float*)d_in[1];
  float* out0 = (float*)d_out;
  float* out1 = out0 + (size_t)M_DIM * NCLUST;

  char* ws = (char*)d_ws;
  u16* zn   = (u16*)ws;                                               // 128 MB
  u16* dnt  = (u16*)(ws + (size_t)M_DIM * K_DIM * 2);                 // 32 MB
  float* colsq   = (float*)(ws + (size_t)M_DIM * K_DIM * 2 + (size_t)N_DIM * K_DIM * 2);
  float* s_accum = colsq + N_DIM;

  zero_kernel<<<(N_DIM + 255) / 256, 256, 0, stream>>>(colsq, N_DIM);
  znorm_copy_kernel<<<M_DIM, 256, 0, stream>>>(z, out1, zn);
  colsq_kernel<<<dim3(N_DIM / 256, N_DIM / 128), 256, 0, stream>>>(D, colsq);
  dnt_kernel<<<dim3(N_DIM / 64, N_DIM / 64), 256, 0, stream>>>(D, colsq, dnt);
  gemm_kernel<<<(M_DIM / BM) * (N_DIM / BN), 512, 0, stream>>>(zn, dnt, s_accum);
  softmax_kernel<<<M_DIM / 256, 256, 0, stream>>>(s_accum, out0);
}

// Round 5
// 474.611 us; speedup vs baseline: 1.7740x; 1.3052x over previous
//
#include <hip/hip_runtime.h>

#define M_DIM 16384
#define N_DIM 4096
#define K_DIM 4096
#define NCLUST 16

#define BM 256
#define BN 256
#define BKB 128               // K-tile in BYTES per row (128 fp8 elements)
#define NT (K_DIM / BKB)      // 32 K-tiles

typedef unsigned short u16;
typedef unsigned char u8;
typedef float floatx4 __attribute__((ext_vector_type(4)));
typedef int int4v __attribute__((ext_vector_type(4)));
typedef int int8v __attribute__((ext_vector_type(8)));

typedef const unsigned int __attribute__((address_space(1))) gu32;
typedef unsigned int __attribute__((address_space(3))) lu32;

// float -> OCP e4m3fn with RNE (values are pre-scaled, |x| << 448)
__device__ __forceinline__ unsigned f2fp8(float x) {
  union { float f; unsigned u; } a; a.f = x;
  unsigned s = (a.u >> 24) & 0x80u;
  float ax = fabsf(x);
  if (ax >= 448.f) return s | 0x7Eu;
  if (ax < 0.015625f) {                       // subnormal: step 2^-9
    unsigned q = (unsigned)rintf(ax * 512.0f);  // 0..8 (8 -> min normal, encodes fine)
    return s | q;
  }
  unsigned u = a.u & 0x7FFFFFFFu;
  u += 0xFFFFFu + ((u >> 20) & 1u);           // RNE into 3-bit mantissa
  unsigned E = u >> 23;
  return s | (((E - 120u) << 3) & 0x78u) | ((u >> 20) & 7u);
}

// ---------------- zero scratch accumulators ----------------
__global__ __launch_bounds__(256) void zero_kernel(float* __restrict__ p, int n) {
  int i = blockIdx.x * 256 + threadIdx.x;
  if (i < n) p[i] = 0.f;
}

// ---------------- z row-normalize -> fp8 (x64), plus copy z -> out1 ----------------
__global__ __launch_bounds__(256) void znorm_copy_kernel(const float* __restrict__ z,
                                                         float* __restrict__ out1,
                                                         u8* __restrict__ zn) {
  const int row = blockIdx.x;
  const int t = threadIdx.x;
  const size_t base = (size_t)row * K_DIM;
  const float4* zr = (const float4*)(z + base);
  float4 v[4];
  float ss = 0.f;
#pragma unroll
  for (int i = 0; i < 4; i++) {
    v[i] = zr[t + i * 256];
    ss += v[i].x * v[i].x + v[i].y * v[i].y + v[i].z * v[i].z + v[i].w * v[i].w;
  }
#pragma unroll
  for (int m = 1; m <= 32; m <<= 1) ss += __shfl_xor(ss, m, 64);
  __shared__ float red[4];
  if ((t & 63) == 0) red[t >> 6] = ss;
  __syncthreads();
  float tot = red[0] + red[1] + red[2] + red[3];
  float sc = 64.0f / fmaxf(sqrtf(tot), 1e-8f);   // x64 scaling folded into normalize
  float4* o1 = (float4*)(out1 + base);
  unsigned* znr = (unsigned*)(zn + base);
#pragma unroll
  for (int i = 0; i < 4; i++) {
    o1[t + i * 256] = v[i];
    unsigned pk = f2fp8(v[i].x * sc) | (f2fp8(v[i].y * sc) << 8) |
                  (f2fp8(v[i].z * sc) << 16) | (f2fp8(v[i].w * sc) << 24);
    znr[t + i * 256] = pk;
  }
}

// ---------------- D column squared-norms ----------------
__global__ __launch_bounds__(256) void colsq_kernel(const float* __restrict__ D,
                                                    float* __restrict__ colsq) {
  const int col = blockIdx.x * 256 + threadIdx.x;
  const int r0 = blockIdx.y * 128;
  float ss = 0.f;
#pragma unroll 4
  for (int r = 0; r < 128; r++) {
    float d = D[(size_t)(r0 + r) * N_DIM + col];
    ss += d * d;
  }
  atomicAdd(&colsq[col], ss);
}

// ---------------- D col-normalize + transpose -> fp8 (x64) DnT[N][K] ----------------
__global__ __launch_bounds__(256) void dnt_kernel(const float* __restrict__ D,
                                                  const float* __restrict__ colsq,
                                                  u8* __restrict__ dnt) {
  __shared__ float tile[64][65];
  const int c0 = blockIdx.x * 64, r0 = blockIdx.y * 64;
  const int t = threadIdx.x;
  const int tr = t >> 4;          // 0..15
  const int tc = (t & 15) * 4;    // 0,4,..,60
#pragma unroll
  for (int i = 0; i < 4; i++) {
    int row = i * 16 + tr;
    float4 v = *(const float4*)(D + (size_t)(r0 + row) * N_DIM + c0 + tc);
    tile[row][tc + 0] = v.x; tile[row][tc + 1] = v.y;
    tile[row][tc + 2] = v.z; tile[row][tc + 3] = v.w;
  }
  __syncthreads();
#pragma unroll
  for (int i = 0; i < 4; i++) {
    int nl = i * 16 + tr;
    float sc = 64.0f / fmaxf(sqrtf(colsq[c0 + nl]), 1e-8f);
    unsigned pk = f2fp8(tile[tc + 0][nl] * sc) | (f2fp8(tile[tc + 1][nl] * sc) << 8) |
                  (f2fp8(tile[tc + 2][nl] * sc) << 16) | (f2fp8(tile[tc + 3][nl] * sc) << 24);
    *(unsigned*)(dnt + (size_t)(c0 + nl) * K_DIM + r0 + tc) = pk;
  }
}

// ---------------- GEMM: 256x256, fp8 e4m3, K=128/MFMA via mfma_scale (unit scales) ----
// Same geometry as the bf16 R4 kernel (rows are 128 B in both): 2-buffer LDS,
// 4 phases/K-tile, slot^(row&7) both-sides swizzle, counted vmcnt(4), setprio.
// Each fragment = 2x ds_read_b128 (32 B/lane = 32 fp8 k-elems); 8 MFMA/phase.
__global__ __launch_bounds__(512, 2) void gemm_kernel(const u8* __restrict__ zn,
                                                      const u8* __restrict__ dnt,
                                                      float* __restrict__ s_accum) {
  __shared__ u8 ldsA[2][BM * BKB];   // 2 x 32 KB
  __shared__ u8 ldsB[2][BN * BKB];   // 2 x 32 KB -> 128 KB

  const int t = threadIdx.x;
  const int w = t >> 6, l = t & 63;
  const int lr = l & 15, lk = l >> 4;

  const int bid = blockIdx.x;
  const int swz = (bid & 7) * 128 + (bid >> 3);
  const int bx = swz & 15, by = swz >> 4;
  const int bm = by * BM, bn = bx * BN;
  const int wm = (w >> 2) * 128, wn = (w & 3) * 64;

  // ---- staging source pointers (pre-swizzled), LDS wave-uniform dests (bytes) ----
  const int tr8 = t >> 3, ts = t & 7;
  const int ssrc = ts ^ (tr8 & 7);
  const u8* pA[2][2]; const u8* pB[2][2];
  int aDst[2][2], bDst[2][2];
#pragma unroll
  for (int mh = 0; mh < 2; mh++)
#pragma unroll
    for (int r = 0; r < 2; r++) {
      int row = mh * 64 + r * 128 + tr8;
      pA[mh][r] = zn + (size_t)(bm + row) * K_DIM + ssrc * 16;
      aDst[mh][r] = (mh * 64 + r * 128) * BKB + w * 1024;
    }
#pragma unroll
  for (int nh = 0; nh < 2; nh++)
#pragma unroll
    for (int r = 0; r < 2; r++) {
      int row = nh * 32 + (2 * r + (t >> 8)) * 64 + (tr8 & 31);
      pB[nh][r] = dnt + (size_t)(bn + row) * K_DIM + ssrc * 16;
      bDst[nh][r] = (nh * 32 + (2 * r + (w >> 2)) * 64 + (w & 3) * 8) * BKB;
    }

#define STAGE_AH(BUF, MH, KT) do { \
    __builtin_amdgcn_global_load_lds((gu32*)(pA[MH][0] + (KT) * BKB), (lu32*)&ldsA[BUF][aDst[MH][0]], 16, 0, 0); \
    __builtin_amdgcn_global_load_lds((gu32*)(pA[MH][1] + (KT) * BKB), (lu32*)&ldsA[BUF][aDst[MH][1]], 16, 0, 0); \
  } while (0)
#define STAGE_BH(BUF, NH, KT) do { \
    __builtin_amdgcn_global_load_lds((gu32*)(pB[NH][0] + (KT) * BKB), (lu32*)&ldsB[BUF][bDst[NH][0]], 16, 0, 0); \
    __builtin_amdgcn_global_load_lds((gu32*)(pB[NH][1] + (KT) * BKB), (lu32*)&ldsB[BUF][bDst[NH][1]], 16, 0, 0); \
  } while (0)

  // ---- ds_read fragment byte offsets (3-bit row swizzle; slot0 = 2*lk) ----
  int aOff[8], bOff[4];
#pragma unroll
  for (int m = 0; m < 8; m++) {
    int row = wm + (m >> 2) * 64 + (m & 3) * 16 + lr;
    aOff[m] = row * BKB + (((lk << 1) ^ (row & 7)) * 16);
  }
#pragma unroll
  for (int n = 0; n < 4; n++) {
    int row = wn + (n >> 1) * 32 + (n & 1) * 16 + lr;
    bOff[n] = row * BKB + (((lk << 1) ^ (row & 7)) * 16);
  }

  int8v af[4], bf[2];
  floatx4 acc[8][4] = {};

#define PHASE(AB, BB, MH, NH, RDA, RDB, STAGE_STMT, WAIT_STMT) do { \
    if (RDA) { \
      _Pragma("unroll") \
      for (int mi = 0; mi < 4; mi++) { \
        int4v lo = *(const int4v*)((AB) + aOff[(MH) * 4 + mi]); \
        int4v hi = *(const int4v*)((AB) + (aOff[(MH) * 4 + mi] ^ 16)); \
        af[mi] = __builtin_shufflevector(lo, hi, 0, 1, 2, 3, 4, 5, 6, 7); \
      } } \
    if (RDB) { \
      _Pragma("unroll") \
      for (int ni = 0; ni < 2; ni++) { \
        int4v lo = *(const int4v*)((BB) + bOff[(NH) * 2 + ni]); \
        int4v hi = *(const int4v*)((BB) + (bOff[(NH) * 2 + ni] ^ 16)); \
        bf[ni] = __builtin_shufflevector(lo, hi, 0, 1, 2, 3, 4, 5, 6, 7); \
      } } \
    STAGE_STMT; \
    WAIT_STMT; \
    __builtin_amdgcn_s_barrier(); \
    asm volatile("s_waitcnt lgkmcnt(0)" ::: "memory"); \
    __builtin_amdgcn_s_setprio(1); \
    _Pragma("unroll") \
    for (int mi = 0; mi < 4; mi++) \
      _Pragma("unroll") \
      for (int ni = 0; ni < 2; ni++) \
        acc[(MH) * 4 + mi][(NH) * 2 + ni] = __builtin_amdgcn_mfma_scale_f32_16x16x128_f8f6f4( \
            af[mi], bf[ni], acc[(MH) * 4 + mi][(NH) * 2 + ni], 0, 0, 0, 127u, 0, 127u); \
    __builtin_amdgcn_s_setprio(0); \
    __builtin_amdgcn_s_barrier(); \
  } while (0)

  // prologue: tile0 fully + Ah0(1), Bh1(1); drain tile0, keep 2 halves in flight
  STAGE_AH(0, 0, 0); STAGE_AH(0, 1, 0); STAGE_BH(0, 0, 0); STAGE_BH(0, 1, 0);
  STAGE_AH(1, 0, 1); STAGE_BH(1, 1, 1);
  asm volatile("s_waitcnt vmcnt(4)" ::: "memory");
  __builtin_amdgcn_s_barrier();

  for (int kt = 0; kt < NT - 2; ++kt) {
    const int cb = kt & 1, nb = cb ^ 1;
    const u8* Ac = ldsA[cb]; const u8* Bc = ldsB[cb];
    PHASE(Ac, Bc, 0, 0, 1, 1, STAGE_AH(nb, 1, kt + 1), ((void)0));
    PHASE(Ac, Bc, 0, 1, 0, 1, STAGE_BH(nb, 0, kt + 1), ((void)0));
    PHASE(Ac, Bc, 1, 1, 1, 0, STAGE_AH(cb, 0, kt + 2), ((void)0));
    PHASE(Ac, Bc, 1, 0, 0, 1, STAGE_BH(cb, 1, kt + 2),
          asm volatile("s_waitcnt vmcnt(4)" ::: "memory"));
  }
  { // kt = NT-2: stage only tile NT-1's remaining halves; full drain at ph4
    const int cb = (NT - 2) & 1, nb = cb ^ 1;
    const u8* Ac = ldsA[cb]; const u8* Bc = ldsB[cb];
    PHASE(Ac, Bc, 0, 0, 1, 1, STAGE_AH(nb, 1, NT - 1), ((void)0));
    PHASE(Ac, Bc, 0, 1, 0, 1, STAGE_BH(nb, 0, NT - 1), ((void)0));
    PHASE(Ac, Bc, 1, 1, 1, 0, ((void)0), ((void)0));
    PHASE(Ac, Bc, 1, 0, 0, 1, ((void)0),
          asm volatile("s_waitcnt vmcnt(0)" ::: "memory"));
  }
  { // kt = NT-1: compute only
    const int cb = (NT - 1) & 1;
    const u8* Ac = ldsA[cb]; const u8* Bc = ldsB[cb];
    PHASE(Ac, Bc, 0, 0, 1, 1, ((void)0), ((void)0));
    PHASE(Ac, Bc, 0, 1, 0, 1, ((void)0), ((void)0));
    PHASE(Ac, Bc, 1, 1, 1, 0, ((void)0), ((void)0));
    PHASE(Ac, Bc, 1, 0, 0, 1, ((void)0), ((void)0));
  }

#undef PHASE
#undef STAGE_AH
#undef STAGE_BH

  // ---- epilogue: per-row sum of squares over this wave's 64 columns ----
  __syncthreads();
  float* red = (float*)&ldsA[0][0];    // [256 rows][4 wave-cols]
#pragma unroll
  for (int m = 0; m < 8; m++) {
#pragma unroll
    for (int r = 0; r < 4; r++) {
      float v = 0.f;
#pragma unroll
      for (int n = 0; n < 4; n++) { float x = acc[m][n][r]; v += x * x; }
      v += __shfl_xor(v, 1, 64);
      v += __shfl_xor(v, 2, 64);
      v += __shfl_xor(v, 4, 64);
      v += __shfl_xor(v, 8, 64);
      if (lr == 0) {
        int lrow = wm + (m >> 2) * 64 + (m & 3) * 16 + lk * 4 + r;
        red[lrow * 4 + (w & 3)] = v;
      }
    }
  }
  __syncthreads();
  if (t < 256) {
    float s = red[t * 4 + 0] + red[t * 4 + 1] + red[t * 4 + 2] + red[t * 4 + 3];
    s_accum[(size_t)(bm + t) * NCLUST + bx] = s;
  }
}

// ---------------- softmax over 16 clusters per row ----------------
__global__ __launch_bounds__(256) void softmax_kernel(const float* __restrict__ s_accum,
                                                      float* __restrict__ out0) {
  int r = blockIdx.x * 256 + threadIdx.x;
  const float4* sp = (const float4*)(s_accum + (size_t)r * 16);
  float v[16];
#pragma unroll
  for (int i = 0; i < 4; i++) {
    float4 a = sp[i];
    v[i * 4 + 0] = a.x; v[i * 4 + 1] = a.y; v[i * 4 + 2] = a.z; v[i * 4 + 3] = a.w;
  }
  // logits = (s_scaled / 2^24) / TEMP ; eta*d cancels in softmax
  const float lsc = 5.9604644775390625e-7f;   // 10 / 2^24
  float mx = -1e30f;
#pragma unroll
  for (int i = 0; i < 16; i++) { v[i] *= lsc; mx = fmaxf(mx, v[i]); }
  float sum = 0.f;
#pragma unroll
  for (int i = 0; i < 16; i++) { v[i] = __expf(v[i] - mx); sum += v[i]; }
  float rs = 1.0f / sum;
  float4* op = (float4*)(out0 + (size_t)r * 16);
#pragma unroll
  for (int i = 0; i < 4; i++) {
    float4 a;
    a.x = v[i * 4 + 0] * rs; a.y = v[i * 4 + 1] * rs;
    a.z = v[i * 4 + 2] * rs; a.w = v[i * 4 + 3] * rs;
    op[i] = a;
  }
}

extern "C" void kernel_launch(void* const* d_in, const int* in_sizes, int n_in,
                              void* d_out, int out_size, void* d_ws, size_t ws_size,
                              hipStream_t stream) {
  const float* z = (const float*)d_in[0];
  const float* D = (const float*)d_in[1];
  float* out0 = (float*)d_out;
  float* out1 = out0 + (size_t)M_DIM * NCLUST;

  char* ws = (char*)d_ws;
  u8* zn   = (u8*)ws;                                                 // 64 MB
  u8* dnt  = (u8*)(ws + (size_t)M_DIM * K_DIM);                       // 16 MB
  float* colsq   = (float*)(ws + (size_t)M_DIM * K_DIM + (size_t)N_DIM * K_DIM);
  float* s_accum = colsq + N_DIM;

  zero_kernel<<<(N_DIM + 255) / 256, 256, 0, stream>>>(colsq, N_DIM);
  znorm_copy_kernel<<<M_DIM, 256, 0, stream>>>(z, out1, zn);
  colsq_kernel<<<dim3(N_DIM / 256, N_DIM / 128), 256, 0, stream>>>(D, colsq);
  dnt_kernel<<<dim3(N_DIM / 64, N_DIM / 64), 256, 0, stream>>>(D, colsq, dnt);
  gemm_kernel<<<(M_DIM / BM) * (N_DIM / BN), 512, 0, stream>>>(zn, dnt, s_accum);
  softmax_kernel<<<M_DIM / 256, 256, 0, stream>>>(s_accum, out0);
}

// Round 6
// 473.652 us; speedup vs baseline: 1.7776x; 1.0020x over previous
//
#include <hip/hip_runtime.h>

#define M_DIM 16384
#define N_DIM 4096
#define K_DIM 4096
#define NCLUST 16

#define BM 256
#define BN 256
#define BKB 128               // K-tile in BYTES per row (128 fp8 elements)
#define NT (K_DIM / BKB)      // 32 K-tiles

typedef unsigned short u16;
typedef unsigned char u8;
typedef float floatx4 __attribute__((ext_vector_type(4)));
typedef int int4v __attribute__((ext_vector_type(4)));
typedef int int8v __attribute__((ext_vector_type(8)));

typedef const unsigned int __attribute__((address_space(1))) gu32;
typedef unsigned int __attribute__((address_space(3))) lu32;

// float -> OCP e4m3fn with RNE (values are pre-scaled, |x| << 448)
__device__ __forceinline__ unsigned f2fp8(float x) {
  union { float f; unsigned u; } a; a.f = x;
  unsigned s = (a.u >> 24) & 0x80u;
  float ax = fabsf(x);
  if (ax >= 448.f) return s | 0x7Eu;
  if (ax < 0.015625f) {                       // subnormal: step 2^-9
    unsigned q = (unsigned)rintf(ax * 512.0f);  // 0..8 (8 -> min normal, encodes fine)
    return s | q;
  }
  unsigned u = a.u & 0x7FFFFFFFu;
  u += 0xFFFFFu + ((u >> 20) & 1u);           // RNE into 3-bit mantissa
  unsigned E = u >> 23;
  return s | (((E - 120u) << 3) & 0x78u) | ((u >> 20) & 7u);
}

// ---------------- zero scratch accumulators ----------------
__global__ __launch_bounds__(256) void zero_kernel(float* __restrict__ p, int n) {
  int i = blockIdx.x * 256 + threadIdx.x;
  if (i < n) p[i] = 0.f;
}

// ---------------- z row-normalize -> fp8 (x64), plus copy z -> out1 ----------------
__global__ __launch_bounds__(256) void znorm_copy_kernel(const float* __restrict__ z,
                                                         float* __restrict__ out1,
                                                         u8* __restrict__ zn) {
  const int row = blockIdx.x;
  const int t = threadIdx.x;
  const size_t base = (size_t)row * K_DIM;
  const float4* zr = (const float4*)(z + base);
  float4 v[4];
  float ss = 0.f;
#pragma unroll
  for (int i = 0; i < 4; i++) {
    v[i] = zr[t + i * 256];
    ss += v[i].x * v[i].x + v[i].y * v[i].y + v[i].z * v[i].z + v[i].w * v[i].w;
  }
#pragma unroll
  for (int m = 1; m <= 32; m <<= 1) ss += __shfl_xor(ss, m, 64);
  __shared__ float red[4];
  if ((t & 63) == 0) red[t >> 6] = ss;
  __syncthreads();
  float tot = red[0] + red[1] + red[2] + red[3];
  float sc = 64.0f / fmaxf(sqrtf(tot), 1e-8f);   // x64 scaling folded into normalize
  float4* o1 = (float4*)(out1 + base);
  unsigned* znr = (unsigned*)(zn + base);
#pragma unroll
  for (int i = 0; i < 4; i++) {
    o1[t + i * 256] = v[i];
    unsigned pk = f2fp8(v[i].x * sc) | (f2fp8(v[i].y * sc) << 8) |
                  (f2fp8(v[i].z * sc) << 16) | (f2fp8(v[i].w * sc) << 24);
    znr[t + i * 256] = pk;
  }
}

// ---------------- D column squared-norms ----------------
__global__ __launch_bounds__(256) void colsq_kernel(const float* __restrict__ D,
                                                    float* __restrict__ colsq) {
  const int col = blockIdx.x * 256 + threadIdx.x;
  const int r0 = blockIdx.y * 128;
  float ss = 0.f;
#pragma unroll 4
  for (int r = 0; r < 128; r++) {
    float d = D[(size_t)(r0 + r) * N_DIM + col];
    ss += d * d;
  }
  atomicAdd(&colsq[col], ss);
}

// ---------------- D col-normalize + transpose -> fp8 (x64) DnT[N][K] ----------------
__global__ __launch_bounds__(256) void dnt_kernel(const float* __restrict__ D,
                                                  const float* __restrict__ colsq,
                                                  u8* __restrict__ dnt) {
  __shared__ float tile[64][65];
  const int c0 = blockIdx.x * 64, r0 = blockIdx.y * 64;
  const int t = threadIdx.x;
  const int tr = t >> 4;          // 0..15
  const int tc = (t & 15) * 4;    // 0,4,..,60
#pragma unroll
  for (int i = 0; i < 4; i++) {
    int row = i * 16 + tr;
    float4 v = *(const float4*)(D + (size_t)(r0 + row) * N_DIM + c0 + tc);
    tile[row][tc + 0] = v.x; tile[row][tc + 1] = v.y;
    tile[row][tc + 2] = v.z; tile[row][tc + 3] = v.w;
  }
  __syncthreads();
#pragma unroll
  for (int i = 0; i < 4; i++) {
    int nl = i * 16 + tr;
    float sc = 64.0f / fmaxf(sqrtf(colsq[c0 + nl]), 1e-8f);
    unsigned pk = f2fp8(tile[tc + 0][nl] * sc) | (f2fp8(tile[tc + 1][nl] * sc) << 8) |
                  (f2fp8(tile[tc + 2][nl] * sc) << 16) | (f2fp8(tile[tc + 3][nl] * sc) << 24);
    *(unsigned*)(dnt + (size_t)(c0 + nl) * K_DIM + r0 + tc) = pk;
  }
}

// ---------------- GEMM: 256x256, fp8 e4m3, K=128/MFMA via mfma_scale (unit scales) ----
// Identical to R5 except __launch_bounds__(512, 1): LDS (128 KiB) already limits
// to 1 block/CU, so the (512,2) declaration only capped VGPRs at 128 and forced
// scratch spill (WRITE_SIZE 216 MB). (512,1) -> 256-VGPR cap, no spill, same
// real occupancy.
__global__ __launch_bounds__(512, 1) void gemm_kernel(const u8* __restrict__ zn,
                                                      const u8* __restrict__ dnt,
                                                      float* __restrict__ s_accum) {
  __shared__ u8 ldsA[2][BM * BKB];   // 2 x 32 KB
  __shared__ u8 ldsB[2][BN * BKB];   // 2 x 32 KB -> 128 KB

  const int t = threadIdx.x;
  const int w = t >> 6, l = t & 63;
  const int lr = l & 15, lk = l >> 4;

  const int bid = blockIdx.x;
  const int swz = (bid & 7) * 128 + (bid >> 3);
  const int bx = swz & 15, by = swz >> 4;
  const int bm = by * BM, bn = bx * BN;
  const int wm = (w >> 2) * 128, wn = (w & 3) * 64;

  // ---- staging source pointers (pre-swizzled), LDS wave-uniform dests (bytes) ----
  const int tr8 = t >> 3, ts = t & 7;
  const int ssrc = ts ^ (tr8 & 7);
  const u8* pA[2][2]; const u8* pB[2][2];
  int aDst[2][2], bDst[2][2];
#pragma unroll
  for (int mh = 0; mh < 2; mh++)
#pragma unroll
    for (int r = 0; r < 2; r++) {
      int row = mh * 64 + r * 128 + tr8;
      pA[mh][r] = zn + (size_t)(bm + row) * K_DIM + ssrc * 16;
      aDst[mh][r] = (mh * 64 + r * 128) * BKB + w * 1024;
    }
#pragma unroll
  for (int nh = 0; nh < 2; nh++)
#pragma unroll
    for (int r = 0; r < 2; r++) {
      int row = nh * 32 + (2 * r + (t >> 8)) * 64 + (tr8 & 31);
      pB[nh][r] = dnt + (size_t)(bn + row) * K_DIM + ssrc * 16;
      bDst[nh][r] = (nh * 32 + (2 * r + (w >> 2)) * 64 + (w & 3) * 8) * BKB;
    }

#define STAGE_AH(BUF, MH, KT) do { \
    __builtin_amdgcn_global_load_lds((gu32*)(pA[MH][0] + (KT) * BKB), (lu32*)&ldsA[BUF][aDst[MH][0]], 16, 0, 0); \
    __builtin_amdgcn_global_load_lds((gu32*)(pA[MH][1] + (KT) * BKB), (lu32*)&ldsA[BUF][aDst[MH][1]], 16, 0, 0); \
  } while (0)
#define STAGE_BH(BUF, NH, KT) do { \
    __builtin_amdgcn_global_load_lds((gu32*)(pB[NH][0] + (KT) * BKB), (lu32*)&ldsB[BUF][bDst[NH][0]], 16, 0, 0); \
    __builtin_amdgcn_global_load_lds((gu32*)(pB[NH][1] + (KT) * BKB), (lu32*)&ldsB[BUF][bDst[NH][1]], 16, 0, 0); \
  } while (0)

  // ---- ds_read fragment byte offsets (3-bit row swizzle; slot0 = 2*lk) ----
  int aOff[8], bOff[4];
#pragma unroll
  for (int m = 0; m < 8; m++) {
    int row = wm + (m >> 2) * 64 + (m & 3) * 16 + lr;
    aOff[m] = row * BKB + (((lk << 1) ^ (row & 7)) * 16);
  }
#pragma unroll
  for (int n = 0; n < 4; n++) {
    int row = wn + (n >> 1) * 32 + (n & 1) * 16 + lr;
    bOff[n] = row * BKB + (((lk << 1) ^ (row & 7)) * 16);
  }

  int8v af[4], bf[2];
  floatx4 acc[8][4] = {};

#define PHASE(AB, BB, MH, NH, RDA, RDB, STAGE_STMT, WAIT_STMT) do { \
    if (RDA) { \
      _Pragma("unroll") \
      for (int mi = 0; mi < 4; mi++) { \
        int4v lo = *(const int4v*)((AB) + aOff[(MH) * 4 + mi]); \
        int4v hi = *(const int4v*)((AB) + (aOff[(MH) * 4 + mi] ^ 16)); \
        af[mi] = __builtin_shufflevector(lo, hi, 0, 1, 2, 3, 4, 5, 6, 7); \
      } } \
    if (RDB) { \
      _Pragma("unroll") \
      for (int ni = 0; ni < 2; ni++) { \
        int4v lo = *(const int4v*)((BB) + bOff[(NH) * 2 + ni]); \
        int4v hi = *(const int4v*)((BB) + (bOff[(NH) * 2 + ni] ^ 16)); \
        bf[ni] = __builtin_shufflevector(lo, hi, 0, 1, 2, 3, 4, 5, 6, 7); \
      } } \
    STAGE_STMT; \
    WAIT_STMT; \
    __builtin_amdgcn_s_barrier(); \
    asm volatile("s_waitcnt lgkmcnt(0)" ::: "memory"); \
    __builtin_amdgcn_s_setprio(1); \
    _Pragma("unroll") \
    for (int mi = 0; mi < 4; mi++) \
      _Pragma("unroll") \
      for (int ni = 0; ni < 2; ni++) \
        acc[(MH) * 4 + mi][(NH) * 2 + ni] = __builtin_amdgcn_mfma_scale_f32_16x16x128_f8f6f4( \
            af[mi], bf[ni], acc[(MH) * 4 + mi][(NH) * 2 + ni], 0, 0, 0, 127u, 0, 127u); \
    __builtin_amdgcn_s_setprio(0); \
    __builtin_amdgcn_s_barrier(); \
  } while (0)

  // prologue: tile0 fully + Ah0(1), Bh1(1); drain tile0, keep 2 halves in flight
  STAGE_AH(0, 0, 0); STAGE_AH(0, 1, 0); STAGE_BH(0, 0, 0); STAGE_BH(0, 1, 0);
  STAGE_AH(1, 0, 1); STAGE_BH(1, 1, 1);
  asm volatile("s_waitcnt vmcnt(4)" ::: "memory");
  __builtin_amdgcn_s_barrier();

  for (int kt = 0; kt < NT - 2; ++kt) {
    const int cb = kt & 1, nb = cb ^ 1;
    const u8* Ac = ldsA[cb]; const u8* Bc = ldsB[cb];
    PHASE(Ac, Bc, 0, 0, 1, 1, STAGE_AH(nb, 1, kt + 1), ((void)0));
    PHASE(Ac, Bc, 0, 1, 0, 1, STAGE_BH(nb, 0, kt + 1), ((void)0));
    PHASE(Ac, Bc, 1, 1, 1, 0, STAGE_AH(cb, 0, kt + 2), ((void)0));
    PHASE(Ac, Bc, 1, 0, 0, 1, STAGE_BH(cb, 1, kt + 2),
          asm volatile("s_waitcnt vmcnt(4)" ::: "memory"));
  }
  { // kt = NT-2: stage only tile NT-1's remaining halves; full drain at ph4
    const int cb = (NT - 2) & 1, nb = cb ^ 1;
    const u8* Ac = ldsA[cb]; const u8* Bc = ldsB[cb];
    PHASE(Ac, Bc, 0, 0, 1, 1, STAGE_AH(nb, 1, NT - 1), ((void)0));
    PHASE(Ac, Bc, 0, 1, 0, 1, STAGE_BH(nb, 0, NT - 1), ((void)0));
    PHASE(Ac, Bc, 1, 1, 1, 0, ((void)0), ((void)0));
    PHASE(Ac, Bc, 1, 0, 0, 1, ((void)0),
          asm volatile("s_waitcnt vmcnt(0)" ::: "memory"));
  }
  { // kt = NT-1: compute only
    const int cb = (NT - 1) & 1;
    const u8* Ac = ldsA[cb]; const u8* Bc = ldsB[cb];
    PHASE(Ac, Bc, 0, 0, 1, 1, ((void)0), ((void)0));
    PHASE(Ac, Bc, 0, 1, 0, 1, ((void)0), ((void)0));
    PHASE(Ac, Bc, 1, 1, 1, 0, ((void)0), ((void)0));
    PHASE(Ac, Bc, 1, 0, 0, 1, ((void)0), ((void)0));
  }

#undef PHASE
#undef STAGE_AH
#undef STAGE_BH

  // ---- epilogue: per-row sum of squares over this wave's 64 columns ----
  __syncthreads();
  float* red = (float*)&ldsA[0][0];    // [256 rows][4 wave-cols]
#pragma unroll
  for (int m = 0; m < 8; m++) {
#pragma unroll
    for (int r = 0; r < 4; r++) {
      float v = 0.f;
#pragma unroll
      for (int n = 0; n < 4; n++) { float x = acc[m][n][r]; v += x * x; }
      v += __shfl_xor(v, 1, 64);
      v += __shfl_xor(v, 2, 64);
      v += __shfl_xor(v, 4, 64);
      v += __shfl_xor(v, 8, 64);
      if (lr == 0) {
        int lrow = wm + (m >> 2) * 64 + (m & 3) * 16 + lk * 4 + r;
        red[lrow * 4 + (w & 3)] = v;
      }
    }
  }
  __syncthreads();
  if (t < 256) {
    float s = red[t * 4 + 0] + red[t * 4 + 1] + red[t * 4 + 2] + red[t * 4 + 3];
    s_accum[(size_t)(bm + t) * NCLUST + bx] = s;
  }
}

// ---------------- softmax over 16 clusters per row ----------------
__global__ __launch_bounds__(256) void softmax_kernel(const float* __restrict__ s_accum,
                                                      float* __restrict__ out0) {
  int r = blockIdx.x * 256 + threadIdx.x;
  const float4* sp = (const float4*)(s_accum + (size_t)r * 16);
  float v[16];
#pragma unroll
  for (int i = 0; i < 4; i++) {
    float4 a = sp[i];
    v[i * 4 + 0] = a.x; v[i * 4 + 1] = a.y; v[i * 4 + 2] = a.z; v[i * 4 + 3] = a.w;
  }
  // logits = (s_scaled / 2^24) / TEMP ; eta*d cancels in softmax
  const float lsc = 5.9604644775390625e-7f;   // 10 / 2^24
  float mx = -1e30f;
#pragma unroll
  for (int i = 0; i < 16; i++) { v[i] *= lsc; mx = fmaxf(mx, v[i]); }
  float sum = 0.f;
#pragma unroll
  for (int i = 0; i < 16; i++) { v[i] = __expf(v[i] - mx); sum += v[i]; }
  float rs = 1.0f / sum;
  float4* op = (float4*)(out0 + (size_t)r * 16);
#pragma unroll
  for (int i = 0; i < 4; i++) {
    float4 a;
    a.x = v[i * 4 + 0] * rs; a.y = v[i * 4 + 1] * rs;
    a.z = v[i * 4 + 2] * rs; a.w = v[i * 4 + 3] * rs;
    op[i] = a;
  }
}

extern "C" void kernel_launch(void* const* d_in, const int* in_sizes, int n_in,
                              void* d_out, int out_size, void* d_ws, size_t ws_size,
                              hipStream_t stream) {
  const float* z = (const float*)d_in[0];
  const float* D = (const float*)d_in[1];
  float* out0 = (float*)d_out;
  float* out1 = out0 + (size_t)M_DIM * NCLUST;

  char* ws = (char*)d_ws;
  u8* zn   = (u8*)ws;                                                 // 64 MB
  u8* dnt  = (u8*)(ws + (size_t)M_DIM * K_DIM);                       // 16 MB
  float* colsq   = (float*)(ws + (size_t)M_DIM * K_DIM + (size_t)N_DIM * K_DIM);
  float* s_accum = colsq + N_DIM;

  zero_kernel<<<(N_DIM + 255) / 256, 256, 0, stream>>>(colsq, N_DIM);
  znorm_copy_kernel<<<M_DIM, 256, 0, stream>>>(z, out1, zn);
  colsq_kernel<<<dim3(N_DIM / 256, N_DIM / 128), 256, 0, stream>>>(D, colsq);
  dnt_kernel<<<dim3(N_DIM / 64, N_DIM / 64), 256, 0, stream>>>(D, colsq, dnt);
  gemm_kernel<<<(M_DIM / BM) * (N_DIM / BN), 512, 0, stream>>>(zn, dnt, s_accum);
  softmax_kernel<<<M_DIM / 256, 256, 0, stream>>>(s_accum, out0);
}